// Round 10
// baseline (112.266 us; speedup 1.0000x reference)
//
#include <hip/hip_runtime.h>

// Event-to-image: B=16, N=500000 events (t,x,y,p) f32 -> (16,720,1280,3) f32.
// Last-event-wins per pixel: p==1 -> (0,255,255); p==0 -> (255,0,255);
// untouched -> (255,255,510). Order-independent via max over
// key = ((event_idx+1)<<1)|p, packed pk = x<<20 | key (31 bits).
//
// R10 = R6/R9 with ONE variable: EVPB 8192 -> 16384 (EPT=64). Halves the
// block count (496): per-block fixed costs (hist zero, scan, 721-entry pref
// publish, 6 barriers) amortize 2x; LDS 70KB -> 2 blocks/CU = 8 waves/CU.
// Probe logic: R8 (smaller tiles, MORE occupancy) regressed badly, so test
// the opposite; deep EPT=64 loops give per-wave ILP to cover HBM latency.

#define WIDTH   1280
#define HEIGHT  720
#define BATCH   16
#define NEV     500000
#define THREADS 256
#define EPT     64
#define EVPB    (THREADS * EPT)             // 16384 events per block
#define BPB     ((NEV + EVPB - 1) / EVPB)   // 31 blocks per batch
#define NBLK    (BATCH * BPB)               // 496
#define PH      (HEIGHT + 1)                // 721 prefix entries per block
#define LUT     1536                        // >= row total (~694 +- 26)

typedef float f4 __attribute__((ext_vector_type(4)));

// ws layout: [0, NBLK*PH*4)=pref_g (1.43 MB); [0x400000, +NBLK*EVPB*4)=bins (32.5 MB)

__global__ __launch_bounds__(THREADS) void scatter_k(const float4* __restrict__ ev,
                                                     unsigned int* __restrict__ pref_g,
                                                     unsigned int* __restrict__ bins) {
    __shared__ unsigned int hist[HEIGHT];
    __shared__ unsigned int offs[HEIGHT];
    __shared__ unsigned int wtot[4];
    __shared__ unsigned int stage[EVPB];     // 64 KB

    int t = threadIdx.x;
    int batch = blockIdx.x / BPB;
    int blk   = blockIdx.x % BPB;
    int ev0   = blk * EVPB;
    int cnt   = NEV - ev0; if (cnt > EVPB) cnt = EVPB;
    const float4* bev = ev + (size_t)batch * NEV + ev0;
    const f4* bevv = (const f4*)bev;

    for (int r = t; r < HEIGHT; r += THREADS) hist[r] = 0u;
    __syncthreads();

    // pass 1: row histogram (streams events; pass 2 re-hits L2/L3)
    for (int k = 0; k < EPT; ++k) {
        int e = t + k * THREADS;
        if (e < cnt) {
            float4 v = bev[e];
            atomicAdd(&hist[(int)v.z], 1u);
        }
    }
    __syncthreads();

    // exclusive prefix over 720 rows: threads 0..239 own 3 rows; shfl wave scan
    unsigned int own = 0u;
    int b3 = t * 3;
    if (t < 240) own = hist[b3] + hist[b3 + 1] + hist[b3 + 2];
    unsigned int incl = own;
    for (int d = 1; d < 64; d <<= 1) {
        unsigned int n = __shfl_up(incl, d);
        if ((t & 63) >= d) incl += n;
    }
    if ((t & 63) == 63) wtot[t >> 6] = incl;
    __syncthreads();
    unsigned int wbase = 0u;
    for (int w = 0; w < (t >> 6); ++w) wbase += wtot[w];
    unsigned int total = wtot[0] + wtot[1] + wtot[2] + wtot[3];   // == cnt
    if (t < 240) {
        unsigned int run = wbase + incl - own;
        offs[b3] = run;      run += hist[b3];
        offs[b3 + 1] = run;  run += hist[b3 + 1];
        offs[b3 + 2] = run;
    }
    __syncthreads();

    // publish per-block row prefix BEFORE pass 2 mutates offs
    unsigned int* pg = pref_g + (size_t)blockIdx.x * PH;
    for (int r = t; r < PH; r += THREADS)
        pg[r] = (r < HEIGHT) ? offs[r] : total;
    __syncthreads();

    // pass 2: re-read (L2/L3 hit; nt = last use) and place sorted into stage
    for (int k = 0; k < EPT; ++k) {
        int e = t + k * THREADS;
        if (e < cnt) {
            f4 v = __builtin_nontemporal_load(&bevv[e]);
            int xi = (int)v.y;
            int yi = (int)v.z;
            unsigned int pbit = (v.w == 1.0f) ? 1u : 0u;
            unsigned int key  = (((unsigned int)(ev0 + e) + 1u) << 1) | pbit;  // 20 bits
            unsigned int pk   = ((unsigned int)xi << 20) | key;
            unsigned int slot = atomicAdd(&offs[yi], 1u);                      // < cnt
            stage[slot] = pk;
        }
    }
    __syncthreads();

    // write the sorted chunk, fully coalesced (keep in L2/L3 for render)
    uint4* dst = (uint4*)(bins + (size_t)blockIdx.x * EVPB);
    const uint4* src = (const uint4*)stage;
    for (int k = t; k < EVPB / 4; k += THREADS)
        dst[k] = src[k];
}

__global__ __launch_bounds__(THREADS) void render_k(const unsigned int* __restrict__ pref_g,
                                                    const unsigned int* __restrict__ bins,
                                                    float4* __restrict__ out) {
    __shared__ unsigned int win[WIDTH];
    __shared__ unsigned int segbase[BPB];
    __shared__ unsigned int segpref[65];     // lanes write [1..64]; reads use [0..BPB]
    __shared__ unsigned short lookup[LUT];   // j -> segment id (O(1) gather)

    int t = threadIdx.x;
    int rowid = blockIdx.x;                  // batch*720 + y
    int batch = rowid / HEIGHT;
    int r     = rowid - batch * HEIGHT;

    for (int x = t; x < WIDTH; x += THREADS) win[x] = 0u;

    unsigned int mycnt = 0u;
    if (t < BPB) {
        const unsigned int* pg = pref_g + (size_t)(batch * BPB + t) * PH + r;
        unsigned int p0 = pg[0], p1 = pg[1];
        segbase[t] = (unsigned int)((batch * BPB + t) * EVPB) + p0;
        mycnt = p1 - p0;
    }
    if (t < 64) {                            // wave-0 inclusive scan (31 counts)
        unsigned int v = mycnt;
        for (int d = 1; d < 64; d <<= 1) {
            unsigned int n = __shfl_up(v, d);
            if (t >= d) v += n;
        }
        if (t == 0) segpref[0] = 0u;
        segpref[t + 1] = v;
        // fill lookup: ~22 independent LDS stores per active thread
        if (t < BPB) {
            unsigned int mybase = v - mycnt;
            unsigned int end = (mybase + mycnt < LUT) ? mybase + mycnt : LUT;
            for (unsigned int j = mybase; j < end; ++j)
                lookup[j] = (unsigned short)t;
        }
    }
    __syncthreads();

    unsigned int total = segpref[BPB];       // ~694
    for (unsigned int j = t; j < total; j += THREADS) {
        int lo;
        if (j < LUT) {
            lo = lookup[j];                  // one LDS read
        } else {                             // impossible in practice; exactness
            lo = 0; int hi = BPB - 1;
            while (lo < hi) {
                int mid = (lo + hi + 1) >> 1;
                if (segpref[mid] <= j) lo = mid; else hi = mid - 1;
            }
        }
        unsigned int pk = bins[segbase[lo] + (j - segpref[lo])];
        atomicMax(&win[pk >> 20], pk & 0xFFFFFu);   // LDS atomic
    }
    __syncthreads();

    // write one image row: 1280 px * 3 ch = 960 float4, coalesced, nontemporal
    f4* orow = (f4*)(out + (size_t)rowid * (WIDTH * 3 / 4));
    for (int j = t; j < WIDTH * 3 / 4; j += THREADS) {
        float vals[4];
#pragma unroll
        for (int c = 0; c < 4; ++c) {
            int fi = j * 4 + c;
            int px = fi / 3;
            int ch = fi - px * 3;
            unsigned int k = win[px];
            float val;
            if (k == 0u) val = (ch == 2) ? 510.0f : 255.0f;
            else if (ch == 2) val = 255.0f;
            else if (ch == 0) val = (k & 1u) ? 0.0f : 255.0f;
            else              val = (k & 1u) ? 255.0f : 0.0f;
            vals[c] = val;
        }
        f4 o = { vals[0], vals[1], vals[2], vals[3] };
        __builtin_nontemporal_store(o, orow + j);
    }
}

extern "C" void kernel_launch(void* const* d_in, const int* in_sizes, int n_in,
                              void* d_out, int out_size, void* d_ws, size_t ws_size,
                              hipStream_t stream) {
    const float4* ev = (const float4*)d_in[0];
    unsigned int* pref_g = (unsigned int*)d_ws;
    unsigned int* bins   = (unsigned int*)((char*)d_ws + 0x400000);
    float4* out = (float4*)d_out;

    scatter_k<<<NBLK, THREADS, 0, stream>>>(ev, pref_g, bins);
    render_k<<<BATCH * HEIGHT, THREADS, 0, stream>>>(pref_g, bins, out);
}

// Round 11
// 94.234 us; speedup vs baseline: 1.1913x; 1.1913x over previous
//
#include <hip/hip_runtime.h>

// Event-to-image: B=16, N=500000 events (t,x,y,p) f32 -> (16,720,1280,3) f32.
// Last-event-wins per pixel: p==1 -> (0,255,255); p==0 -> (255,0,255);
// untouched -> (255,255,510). Order-independent via max over
// key = ((event_idx+1)<<1)|p  (20 bits; i+1 <= 500000 < 2^19),
// packed pk = pos<<20 | key with pos = (y&1)*1280 + x (12 bits) -- 2-ROW BANDS.
//
// R11: R6 structure (two-pass scatter + LDS stage + coalesced chunk write)
// with 360 two-row bands instead of 720 row bins, and 512-thread blocks.
// Rationale: R10 proved scatter is occupancy-bound (8 waves/CU regressed
// 14us); bands halve the LDS tables -> 34.9KB -> 4 blocks/CU x 8 waves =
// 32 waves/CU (2x R6's 16). Per-block publish drops 721 -> 361 entries.
// Render: one block per (batch, row-pair), win[2560], ~1389 events in
// ~22-event segment runs, 30KB contiguous nt output per block.

#define WIDTH   1280
#define HEIGHT  720
#define BATCH   16
#define NEV     500000
#define THREADS 512                         // scatter block
#define EPT     16
#define EVPB    (THREADS * EPT)             // 8192 events per block
#define BPB     ((NEV + EVPB - 1) / EVPB)   // 62 blocks per batch
#define NBLK    (BATCH * BPB)               // 992
#define NBANDS  360                         // 2-row bands per batch
#define PH      (NBANDS + 1)                // 361 prefix entries per block
#define RTHREADS 256                        // render block

typedef float f4 __attribute__((ext_vector_type(4)));

// ws layout: [0, NBLK*PH*4)=pref_g (1.43 MB); [0x400000, +NBLK*EVPB*4)=bins (32.5 MB)

__global__ __launch_bounds__(THREADS, 8) void scatter_k(const float4* __restrict__ ev,
                                                        unsigned int* __restrict__ pref_g,
                                                        unsigned int* __restrict__ bins) {
    __shared__ unsigned int hist[NBANDS];
    __shared__ unsigned int offs[NBANDS];
    __shared__ unsigned int wtot[8];
    __shared__ unsigned int stage[EVPB];     // 32 KB

    int t = threadIdx.x;
    int batch = blockIdx.x / BPB;
    int blk   = blockIdx.x % BPB;
    int ev0   = blk * EVPB;
    int cnt   = NEV - ev0; if (cnt > EVPB) cnt = EVPB;
    const float4* bev = ev + (size_t)batch * NEV + ev0;
    const f4* bevv = (const f4*)bev;

    if (t < NBANDS) { hist[t] = 0u; }
    __syncthreads();

    // pass 1: band histogram (normal loads -> prime L2/L3 for pass 2)
    for (int k = 0; k < EPT; ++k) {
        int e = t + k * THREADS;
        if (e < cnt) {
            float4 v = bev[e];
            atomicAdd(&hist[((int)v.z) >> 1], 1u);
        }
    }
    __syncthreads();

    // exclusive prefix over 360 bands: threads 0..89 own 4 bands; 2-wave scan
    unsigned int own = 0u;
    int b4 = t * 4;
    if (t < 90) own = hist[b4] + hist[b4 + 1] + hist[b4 + 2] + hist[b4 + 3];
    unsigned int incl = own;
    for (int d = 1; d < 64; d <<= 1) {
        unsigned int n = __shfl_up(incl, d);
        if ((t & 63) >= d) incl += n;
    }
    if ((t & 63) == 63) wtot[t >> 6] = incl;   // waves 2..7 write 0
    __syncthreads();
    unsigned int wbase = 0u;
    for (int w = 0; w < (t >> 6); ++w) wbase += wtot[w];
    unsigned int total = 0u;
    for (int w = 0; w < 8; ++w) total += wtot[w];        // == cnt
    if (t < 90) {
        unsigned int run = wbase + incl - own;
        offs[b4] = run;          run += hist[b4];
        offs[b4 + 1] = run;      run += hist[b4 + 1];
        offs[b4 + 2] = run;      run += hist[b4 + 2];
        offs[b4 + 3] = run;
    }
    __syncthreads();

    // publish per-block band prefix BEFORE pass 2 mutates offs
    unsigned int* pg = pref_g + (size_t)blockIdx.x * PH;
    if (t < PH) pg[t] = (t < NBANDS) ? offs[t] : total;
    __syncthreads();

    // pass 2: re-read (L2/L3 hit; nt = last use), rank, place sorted in stage
    for (int k = 0; k < EPT; ++k) {
        int e = t + k * THREADS;
        if (e < cnt) {
            f4 v = __builtin_nontemporal_load(&bevv[e]);
            int xi = (int)v.y;
            int yi = (int)v.z;
            unsigned int pbit = (v.w == 1.0f) ? 1u : 0u;
            unsigned int pos  = ((unsigned int)(yi & 1)) * 1280u + (unsigned int)xi;
            unsigned int pk   = (pos << 20)
                              | (((unsigned int)(ev0 + e) + 1u) << 1) | pbit;
            unsigned int slot = atomicAdd(&offs[yi >> 1], 1u);   // < cnt
            stage[slot] = pk;
        }
    }
    __syncthreads();

    // write the sorted chunk, fully coalesced (keep in L2/L3 for render)
    uint4* dst = (uint4*)(bins + (size_t)blockIdx.x * EVPB);
    const uint4* src = (const uint4*)stage;
    for (int k = t; k < EVPB / 4; k += THREADS)
        dst[k] = src[k];
}

__global__ __launch_bounds__(RTHREADS) void render_k(const unsigned int* __restrict__ pref_g,
                                                     const unsigned int* __restrict__ bins,
                                                     float4* __restrict__ out) {
    __shared__ unsigned int win[2 * WIDTH];  // 2560 px, 10 KB
    __shared__ unsigned int segbase[BPB];
    __shared__ unsigned int segpref[65];

    int t = threadIdx.x;
    int bandid = blockIdx.x;                 // batch*360 + band
    int batch = bandid / NBANDS;
    int band  = bandid - batch * NBANDS;

    for (int x = t; x < 2 * WIDTH; x += RTHREADS) win[x] = 0u;

    unsigned int mycnt = 0u;
    if (t < BPB) {
        const unsigned int* pg = pref_g + (size_t)(batch * BPB + t) * PH + band;
        unsigned int p0 = pg[0], p1 = pg[1];
        segbase[t] = (unsigned int)((batch * BPB + t) * EVPB) + p0;
        mycnt = p1 - p0;
    }
    if (t < 64) {                            // wave-0 inclusive scan of 62 counts
        unsigned int v = mycnt;
        for (int d = 1; d < 64; d <<= 1) {
            unsigned int n = __shfl_up(v, d);
            if (t >= d) v += n;
        }
        if (t == 0) segpref[0] = 0u;
        segpref[t + 1] = v;
    }
    __syncthreads();

    unsigned int total = segpref[BPB];       // ~1389
    for (unsigned int j = t; j < total; j += RTHREADS) {
        int lo = 0, hi = BPB - 1;            // largest s with segpref[s] <= j
        while (lo < hi) {
            int mid = (lo + hi + 1) >> 1;
            if (segpref[mid] <= j) lo = mid; else hi = mid - 1;
        }
        unsigned int pk = bins[segbase[lo] + (j - segpref[lo])];
        atomicMax(&win[pk >> 20], pk & 0xFFFFFu);   // LDS atomic
    }
    __syncthreads();

    // write two image rows: 2560 px * 3 ch = 1920 float4, contiguous, nt
    f4* orow = (f4*)out + (size_t)bandid * (2 * WIDTH * 3 / 4);
    for (int j = t; j < 2 * WIDTH * 3 / 4; j += RTHREADS) {
        float vals[4];
#pragma unroll
        for (int c = 0; c < 4; ++c) {
            int fi = j * 4 + c;
            int px = fi / 3;
            int ch = fi - px * 3;
            unsigned int k = win[px];
            float val;
            if (k == 0u) val = (ch == 2) ? 510.0f : 255.0f;
            else if (ch == 2) val = 255.0f;
            else if (ch == 0) val = (k & 1u) ? 0.0f : 255.0f;
            else              val = (k & 1u) ? 255.0f : 0.0f;
            vals[c] = val;
        }
        f4 o = { vals[0], vals[1], vals[2], vals[3] };
        __builtin_nontemporal_store(o, orow + j);
    }
}

extern "C" void kernel_launch(void* const* d_in, const int* in_sizes, int n_in,
                              void* d_out, int out_size, void* d_ws, size_t ws_size,
                              hipStream_t stream) {
    const float4* ev = (const float4*)d_in[0];
    unsigned int* pref_g = (unsigned int*)d_ws;
    unsigned int* bins   = (unsigned int*)((char*)d_ws + 0x400000);
    float4* out = (float4*)d_out;

    scatter_k<<<NBLK, THREADS, 0, stream>>>(ev, pref_g, bins);
    render_k<<<BATCH * NBANDS, RTHREADS, 0, stream>>>(pref_g, bins, out);
}

// Round 12
// 81.932 us; speedup vs baseline: 1.3702x; 1.1502x over previous
//
#include <hip/hip_runtime.h>

// Event-to-image: B=16, N=500000 events (t,x,y,p) f32 -> (16,720,1280,3) f32.
// Last-event-wins per pixel: p==1 -> (0,255,255); p==0 -> (255,0,255);
// untouched -> (255,255,510). Order-independent via max over
// key = ((event_idx+1)<<1)|p  (20 bits), pk = pos<<20 | key,
// pos = (y&1)*1280 + x (12 bits) -- 2-row bands.
//
// R12 = R11 (94.2us: bands + 512-thr scatter, 32 waves/CU) with ONE change:
// pass 2's 128MB global re-read (L3 round-trip; 992 live chunks >> 4MB/XCD L2)
// replaced by register-cached packed events pkd[16] (16 VGPRs; R4's idea but
// at 1/3 the register load and 2x the occupancy). launch_bounds(512,8) pins
// VGPR<=64 so 4 blocks/CU x 8 waves = 32 waves/CU is kept. Pass-1 loads are
// nontemporal (single use now). Staged copy-out + R11 render unchanged.

#define WIDTH   1280
#define HEIGHT  720
#define BATCH   16
#define NEV     500000
#define THREADS 512                         // scatter block
#define EPT     16
#define EVPB    (THREADS * EPT)             // 8192 events per block
#define BPB     ((NEV + EVPB - 1) / EVPB)   // 62 blocks per batch
#define NBLK    (BATCH * BPB)               // 992
#define NBANDS  360                         // 2-row bands per batch
#define PH      (NBANDS + 1)                // 361 prefix entries per block
#define RTHREADS 256                        // render block

typedef float f4 __attribute__((ext_vector_type(4)));

// ws layout: [0, NBLK*PH*4)=pref_g (1.43 MB); [0x400000, +NBLK*EVPB*4)=bins (32.5 MB)

__global__ __launch_bounds__(THREADS, 8) void scatter_k(const float4* __restrict__ ev,
                                                        unsigned int* __restrict__ pref_g,
                                                        unsigned int* __restrict__ bins) {
    __shared__ unsigned int hist[NBANDS];
    __shared__ unsigned int offs[NBANDS];
    __shared__ unsigned int wtot[8];
    __shared__ unsigned int stage[EVPB];     // 32 KB  (total ~34.9 KB -> 4 blocks/CU)

    int t = threadIdx.x;
    int batch = blockIdx.x / BPB;
    int blk   = blockIdx.x % BPB;
    int ev0   = blk * EVPB;
    int cnt   = NEV - ev0; if (cnt > EVPB) cnt = EVPB;
    const f4* bevv = (const f4*)(ev + (size_t)batch * NEV + ev0);

    if (t < NBANDS) hist[t] = 0u;
    __syncthreads();

    // pass 1: ONE global read (nt, single use), pack to registers, histogram
    unsigned int pkd[EPT];                   // y<<12 | x<<1 | p ; 0xFFFFFFFF = tail
#pragma unroll
    for (int k = 0; k < EPT; ++k) {
        int e = t + k * THREADS;
        unsigned int c = 0xFFFFFFFFu;
        if (e < cnt) {
            f4 v = __builtin_nontemporal_load(&bevv[e]);
            unsigned int yi = (unsigned int)(int)v.z;
            unsigned int xi = (unsigned int)(int)v.y;
            unsigned int pb = (v.w == 1.0f) ? 1u : 0u;
            c = (yi << 12) | (xi << 1) | pb;
            atomicAdd(&hist[yi >> 1], 1u);
        }
        pkd[k] = c;
    }
    __syncthreads();

    // exclusive prefix over 360 bands: threads 0..89 own 4 bands; shfl scan
    unsigned int own = 0u;
    int b4 = t * 4;
    if (t < 90) own = hist[b4] + hist[b4 + 1] + hist[b4 + 2] + hist[b4 + 3];
    unsigned int incl = own;
    for (int d = 1; d < 64; d <<= 1) {
        unsigned int n = __shfl_up(incl, d);
        if ((t & 63) >= d) incl += n;
    }
    if ((t & 63) == 63) wtot[t >> 6] = incl;   // waves 2..7 contribute 0
    __syncthreads();
    unsigned int wbase = 0u;
    for (int w = 0; w < (t >> 6); ++w) wbase += wtot[w];
    unsigned int total = 0u;
    for (int w = 0; w < 8; ++w) total += wtot[w];        // == cnt
    if (t < 90) {
        unsigned int run = wbase + incl - own;
        offs[b4] = run;          run += hist[b4];
        offs[b4 + 1] = run;      run += hist[b4 + 1];
        offs[b4 + 2] = run;      run += hist[b4 + 2];
        offs[b4 + 3] = run;
    }
    __syncthreads();

    // publish per-block band prefix BEFORE pass 2 mutates offs
    unsigned int* pg = pref_g + (size_t)blockIdx.x * PH;
    if (t < PH) pg[t] = (t < NBANDS) ? offs[t] : total;
    __syncthreads();

    // pass 2: from REGISTERS (no global re-read), rank, place sorted in stage
#pragma unroll
    for (int k = 0; k < EPT; ++k) {
        unsigned int c = pkd[k];
        if (c != 0xFFFFFFFFu) {
            unsigned int yi  = c >> 12;
            unsigned int xi  = (c >> 1) & 0x7FFu;
            unsigned int pos = (yi & 1u) * 1280u + xi;
            unsigned int e   = (unsigned int)(t + k * THREADS);
            unsigned int pk  = (pos << 20)
                             | (((unsigned int)ev0 + e + 1u) << 1) | (c & 1u);
            unsigned int slot = atomicAdd(&offs[yi >> 1], 1u);   // < cnt
            stage[slot] = pk;
        }
    }
    __syncthreads();

    // write the sorted chunk, fully coalesced (keep in L2/L3 for render)
    uint4* dst = (uint4*)(bins + (size_t)blockIdx.x * EVPB);
    const uint4* src = (const uint4*)stage;
    for (int k = t; k < EVPB / 4; k += THREADS)
        dst[k] = src[k];
}

__global__ __launch_bounds__(RTHREADS) void render_k(const unsigned int* __restrict__ pref_g,
                                                     const unsigned int* __restrict__ bins,
                                                     float4* __restrict__ out) {
    __shared__ unsigned int win[2 * WIDTH];  // 2560 px, 10 KB
    __shared__ unsigned int segbase[BPB];
    __shared__ unsigned int segpref[65];

    int t = threadIdx.x;
    int bandid = blockIdx.x;                 // batch*360 + band
    int batch = bandid / NBANDS;
    int band  = bandid - batch * NBANDS;

    for (int x = t; x < 2 * WIDTH; x += RTHREADS) win[x] = 0u;

    unsigned int mycnt = 0u;
    if (t < BPB) {
        const unsigned int* pg = pref_g + (size_t)(batch * BPB + t) * PH + band;
        unsigned int p0 = pg[0], p1 = pg[1];
        segbase[t] = (unsigned int)((batch * BPB + t) * EVPB) + p0;
        mycnt = p1 - p0;
    }
    if (t < 64) {                            // wave-0 inclusive scan of 62 counts
        unsigned int v = mycnt;
        for (int d = 1; d < 64; d <<= 1) {
            unsigned int n = __shfl_up(v, d);
            if (t >= d) v += n;
        }
        if (t == 0) segpref[0] = 0u;
        segpref[t + 1] = v;
    }
    __syncthreads();

    unsigned int total = segpref[BPB];       // ~1389
    for (unsigned int j = t; j < total; j += RTHREADS) {
        int lo = 0, hi = BPB - 1;            // largest s with segpref[s] <= j
        while (lo < hi) {
            int mid = (lo + hi + 1) >> 1;
            if (segpref[mid] <= j) lo = mid; else hi = mid - 1;
        }
        unsigned int pk = bins[segbase[lo] + (j - segpref[lo])];
        atomicMax(&win[pk >> 20], pk & 0xFFFFFu);   // LDS atomic
    }
    __syncthreads();

    // write two image rows: 2560 px * 3 ch = 1920 float4, contiguous, nt
    f4* orow = (f4*)out + (size_t)bandid * (2 * WIDTH * 3 / 4);
    for (int j = t; j < 2 * WIDTH * 3 / 4; j += RTHREADS) {
        float vals[4];
#pragma unroll
        for (int c = 0; c < 4; ++c) {
            int fi = j * 4 + c;
            int px = fi / 3;
            int ch = fi - px * 3;
            unsigned int k = win[px];
            float val;
            if (k == 0u) val = (ch == 2) ? 510.0f : 255.0f;
            else if (ch == 2) val = 255.0f;
            else if (ch == 0) val = (k & 1u) ? 0.0f : 255.0f;
            else              val = (k & 1u) ? 255.0f : 0.0f;
            vals[c] = val;
        }
        f4 o = { vals[0], vals[1], vals[2], vals[3] };
        __builtin_nontemporal_store(o, orow + j);
    }
}

extern "C" void kernel_launch(void* const* d_in, const int* in_sizes, int n_in,
                              void* d_out, int out_size, void* d_ws, size_t ws_size,
                              hipStream_t stream) {
    const float4* ev = (const float4*)d_in[0];
    unsigned int* pref_g = (unsigned int*)d_ws;
    unsigned int* bins   = (unsigned int*)((char*)d_ws + 0x400000);
    float4* out = (float4*)d_out;

    scatter_k<<<NBLK, THREADS, 0, stream>>>(ev, pref_g, bins);
    render_k<<<BATCH * NBANDS, RTHREADS, 0, stream>>>(pref_g, bins, out);
}